// Round 1
// baseline (82.367 us; speedup 1.0000x reference)
//
#include <hip/hip_runtime.h>

// Problem constants (from reference setup_inputs)
#define LATDIM 128     // d
#define ANUM   64      // anchor sets A
#define NNODES 10000   // N
#define PERIOD 625     // period of (64*i mod 10000); gcd(64,10000)=16
#define TN     16      // n per main block (10000 = 625 * 16, no tail)
#define ABLK   64      // anchor blocks in prep
#define SBLK   625     // s blocks in prep (one per residue s)

// ---------------------------------------------------------------------------
// Verified algebra (r3/r4/r6 passed, absmax 9.8e-4):
//   out[n,o] = (1/A)*sum_a dists[a,n]*P[a,o] + T2b[n%625,o]
//   P[a,o]   = sum_k E[anchor[a],k]*W[o,k]
//   T2b[s,o] = b[o] + (1/A)*sum_k S[s,k]*W[o,128+k], S[s,k]=sum_a E[(64s+a)%N,k]
//
// r8 delta: OCCUPANCY restructure (theory: both kernels latency-bound at
// <=1-2 blocks/CU, not BW/VALU-bound — roofline says ~10 us total).
//  prep: 165 -> 689 blocks. One block per anchor (64) + one block per s
//        (625; rows (64s+a)%N are a contiguous 64-row span, single wrap).
//        W is read DIRECT from global (L1/L2-hot, each 64B line reused 4x
//        by its lane) instead of a 66KB LDS stage -> LDS 5.5KB, no
//        2-blocks/CU cap, no 16-float4-per-thread stage latency.
//        Phase-1 row sums are float4, full-row-pair coalesced (1KB/instr).
//  main: TN 32 -> 16: 625 blocks (ceil 3/CU vs 2 full T32 on 57 CUs),
//        acc[8], a-loop unroll 4 (4 s_load_dwordx8 + 4 ds_read in flight).
//        10000 = 625*16 exactly -> live/clamp logic deleted.
// r5 lesson kept: no cross-block flags, no p[64] VGPR arrays.
// ---------------------------------------------------------------------------

__global__ __launch_bounds__(256) void prep_kernel(
    const float* __restrict__ embeds,   // [N, d] fp32
    const float* __restrict__ W,        // [d, 2d] fp32 row-major
    const float* __restrict__ b,        // [d] fp32
    const int*   __restrict__ anchor,   // [A] int32
    float* __restrict__ P,              // [A, d]   (ws)
    float* __restrict__ T2b)            // [625, d] (ws)
{
    __shared__ float X_s[LATDIM];       // 512 B: the 128-vector fed to W
    __shared__ float R_s[LATDIM];       // 512 B: split-k partials
    __shared__ float Xp[8][LATDIM];     // 4 KB: phase-1 row-group partials
    const int tid = threadIdx.x;
    const float4* X_s4 = (const float4*)X_s;

    if (blockIdx.x < ABLK) {
        // ---- P[a,:] = E[anchor[a],:] @ W[:, 0:128] ----
        const int a = blockIdx.x;
        if (tid < 32) {
            ((float4*)X_s)[tid] =
                *((const float4*)(embeds + (size_t)anchor[a] * LATDIM) + tid);
        }
        __syncthreads();

        const int o = tid & 127;            // output channel
        const int h = tid >> 7;             // split-k half
        const float4* Wr = (const float4*)(W + (size_t)o * (2 * LATDIM) + h * 64);
        float acc = 0.f;
        #pragma unroll
        for (int k4 = 0; k4 < 16; ++k4) {
            float4 w4 = Wr[k4];
            float4 x4 = X_s4[h * 16 + k4];          // LDS broadcast
            acc += w4.x * x4.x + w4.y * x4.y + w4.z * x4.z + w4.w * x4.w;
        }
        if (h == 1) R_s[o] = acc;
        __syncthreads();
        if (h == 0) P[(size_t)a * LATDIM + o] = acc + R_s[o];
    } else {
        // ---- T2b[s,:] = b + (1/A) * S[s,:] @ W[:, 128:256] ----
        const int s = blockIdx.x - ABLK;            // 0..624
        const int row0 = (64 * s) % NNODES;         // contiguous span start

        // Phase 1: S[s,:] = sum of 64 contiguous (mod N) embed rows.
        // Thread (hg, c4) sums rows {row0+8i+hg} at float4-column c4.
        // A wave covers 2 adjacent full rows per load instr (1 KB contiguous).
        const int c4 = tid & 31;                    // float4 column 0..31
        const int hg = tid >> 5;                    // row group 0..7
        float4 sum = {0.f, 0.f, 0.f, 0.f};
        #pragma unroll
        for (int i = 0; i < 8; ++i) {
            int row = row0 + 8 * i + hg;
            if (row >= NNODES) row -= NNODES;       // single wrap suffices
            float4 v = *((const float4*)(embeds + (size_t)row * LATDIM) + c4);
            sum.x += v.x; sum.y += v.y; sum.z += v.z; sum.w += v.w;
        }
        ((float4*)&Xp[hg][0])[c4] = sum;
        __syncthreads();
        if (tid < LATDIM) {                         // conflict-free combine
            float t = Xp[0][tid];
            #pragma unroll
            for (int g = 1; g < 8; ++g) t += Xp[g][tid];
            X_s[tid] = t;
        }
        __syncthreads();

        // Phase 2: matvec with second W half, split-k across h.
        const int o = tid & 127;
        const int h = tid >> 7;
        const float4* Wr =
            (const float4*)(W + (size_t)o * (2 * LATDIM) + LATDIM + h * 64);
        float acc = 0.f;
        #pragma unroll
        for (int k4 = 0; k4 < 16; ++k4) {
            float4 w4 = Wr[k4];
            float4 x4 = X_s4[h * 16 + k4];          // LDS broadcast
            acc += w4.x * x4.x + w4.y * x4.y + w4.z * x4.z + w4.w * x4.w;
        }
        if (h == 1) R_s[o] = acc;
        __syncthreads();
        if (h == 0)
            T2b[(size_t)s * LATDIM + o] =
                b[o] + (acc + R_s[o]) * (1.0f / ANUM);
    }
}

// out[n,o] = (1/A) * sum_a dists[a,n] * P[a,o] + T2b[n%625, o]
__global__ __launch_bounds__(256) void main_kernel(
    const float* __restrict__ dists,    // [A, N] fp32
    const float* __restrict__ P,        // [A, d]
    const float* __restrict__ T2b,      // [625, d]
    float* __restrict__ out)            // [N, d] fp32
{
    __shared__ float P_s[ANUM * LATDIM];   // 32 KB (5 blocks/CU cap — fine)
    const int tid = threadIdx.x;

    {   // stage P, coalesced float4 (8 iters: 2048 float4 / 256 threads)
        float4* P_s4 = (float4*)P_s;
        const float4* Pg = (const float4*)P;
        #pragma unroll
        for (int it = 0; it < (ANUM * LATDIM / 4) / 256; ++it)
            P_s4[it * 256 + tid] = Pg[it * 256 + tid];
    }
    __syncthreads();

    const int lane = tid & 63;
    const int w    = __builtin_amdgcn_readfirstlane(tid >> 6);  // uniform 0..3
    const int o    = (w & 1) * 64 + lane;   // output channel
    const int nc   = w >> 1;                // n-chunk within block
    const int nb   = blockIdx.x * TN + nc * 8;   // uniform; always in-range

    float acc[8] = {};
    #pragma unroll 4
    for (int a = 0; a < ANUM; ++a) {
        const float p = P_s[a * LATDIM + o];                 // per-lane LDS
        const float* __restrict__ drow = dists + (size_t)a * NNODES + nb;
        #pragma unroll
        for (int j = 0; j < 8; ++j)
            acc[j] += drow[j] * p;                           // uniform s_loads
    }

    #pragma unroll
    for (int j = 0; j < 8; ++j) {
        const int n = nb + j;
        const int s = n % PERIOD;
        out[(size_t)n * LATDIM + o] =
            acc[j] * (1.0f / ANUM) + T2b[(size_t)s * LATDIM + o];
    }
}

extern "C" void kernel_launch(void* const* d_in, const int* in_sizes, int n_in,
                              void* d_out, int out_size, void* d_ws, size_t ws_size,
                              hipStream_t stream) {
    const float* embeds = (const float*)d_in[0];   // [10000,128] fp32
    const float* dists  = (const float*)d_in[1];   // [64,10000]  fp32
    const float* W      = (const float*)d_in[2];   // [128,256]   fp32
    const float* b      = (const float*)d_in[3];   // [128]       fp32
    const int*   anchor = (const int*)d_in[4];     // [64]        int32
    float* out = (float*)d_out;                    // [10000,128] fp32

    float* P   = (float*)d_ws;            // 64*128 floats   = 32 KB
    float* T2b = P + ANUM * LATDIM;       // 625*128 floats  = 320 KB

    prep_kernel<<<ABLK + SBLK, 256, 0, stream>>>(embeds, W, b, anchor, P, T2b);
    main_kernel<<<NNODES / TN, 256, 0, stream>>>(dists, P, T2b, out);
}